// Round 2
// baseline (603.181 us; speedup 1.0000x reference)
//
#include <hip/hip_runtime.h>
#include <hip/hip_bf16.h>

// Problem: B=2, T=2048, C=1024, H=16, D=64. Tensors stored f32; compute bf16 MFMA.
#define Bb 2
#define Tt 2048
#define Cc 1024
#define Hh 16
#define Dd 64

typedef __bf16 bf16x8 __attribute__((ext_vector_type(8)));
typedef float f32x4 __attribute__((ext_vector_type(4)));

#define MFMA16(a, b, c) __builtin_amdgcn_mfma_f32_16x16x32_bf16((a), (b), (c), 0, 0, 0)

__device__ __forceinline__ bf16x8 ldg8(const __hip_bfloat16* p) {
  return *reinterpret_cast<const bf16x8*>(p);
}

// ---------------------------------------------------------------------------
// f32 -> bf16 elementwise cast (n divisible by 1024)
// ---------------------------------------------------------------------------
__global__ __launch_bounds__(256) void cvt_f32_bf16(
    const float* __restrict__ in, __hip_bfloat16* __restrict__ out, int n) {
  const int i = (blockIdx.x * 256 + threadIdx.x) * 4;
  if (i + 3 < n) {
    const float4 v = *reinterpret_cast<const float4*>(in + i);
    out[i + 0] = __float2bfloat16(v.x);
    out[i + 1] = __float2bfloat16(v.y);
    out[i + 2] = __float2bfloat16(v.z);
    out[i + 3] = __float2bfloat16(v.w);
  }
}

// ---------------------------------------------------------------------------
// Transpose+cast: in f32 [R][Cn] row-major -> out bf16 [Cn][R]
// ---------------------------------------------------------------------------
__global__ __launch_bounds__(256) void transpose_cvt(
    const float* __restrict__ in, __hip_bfloat16* __restrict__ out,
    int R, int Cn) {
  __shared__ float tile[32][33];
  const int c0 = blockIdx.x * 32, r0 = blockIdx.y * 32;
  const int tx = threadIdx.x, ty = threadIdx.y;  // block (32,8)
#pragma unroll
  for (int i = 0; i < 32; i += 8)
    tile[ty + i][tx] = in[(size_t)(r0 + ty + i) * Cn + c0 + tx];
  __syncthreads();
#pragma unroll
  for (int i = 0; i < 32; i += 8)
    out[(size_t)(c0 + ty + i) * R + r0 + tx] = __float2bfloat16(tile[tx][ty + i]);
}

// ---------------------------------------------------------------------------
// QKV GEMM: xb[4096,1024](bf16) @ WT([3072,1024] bf16) + b(f32)
//   -> Q,K [B,H,T,D] bf16, V^T [B,H,D,T] bf16
// Block: 256 thr (4 waves). Block tile 64(M)x64(N).
// ---------------------------------------------------------------------------
__global__ __launch_bounds__(256) void qkv_gemm(
    const __hip_bfloat16* __restrict__ x, const __hip_bfloat16* __restrict__ WT,
    const float* __restrict__ bias,
    __hip_bfloat16* __restrict__ Q, __hip_bfloat16* __restrict__ Kd,
    __hip_bfloat16* __restrict__ VT) {
  const int wave = threadIdx.x >> 6;
  const int lane = threadIdx.x & 63;
  const int l16 = lane & 15, quad = lane >> 4;
  const int m0 = blockIdx.y * 64 + wave * 16;
  const int n0 = blockIdx.x * 64;

  f32x4 acc[4] = {};
  const __hip_bfloat16* arow = x + (size_t)(m0 + l16) * Cc + quad * 8;
#pragma unroll 4
  for (int k0 = 0; k0 < Cc; k0 += 32) {
    bf16x8 af = ldg8(arow + k0);
#pragma unroll
    for (int c = 0; c < 4; ++c) {
      bf16x8 bf = ldg8(WT + (size_t)(n0 + c * 16 + l16) * Cc + k0 + quad * 8);
      acc[c] = MFMA16(af, bf, acc[c]);
    }
  }

  // C/D layout: row = quad*4+r, col = l16.
#pragma unroll
  for (int c = 0; c < 4; ++c) {
    const int n = n0 + c * 16 + l16;
    const float bv = bias[n];
    const int sect = n >> 10;  // 0=Q 1=K 2=V
    const int ch = n & 1023;
    const int h = ch >> 6, d = ch & 63;
#pragma unroll
    for (int r = 0; r < 4; ++r) {
      const int m = m0 + quad * 4 + r;
      const int b = m >> 11, t = m & 2047;
      const __hip_bfloat16 o = __float2bfloat16(acc[c][r] + bv);
      const int bh = b * Hh + h;
      if (sect == 0)      Q[((size_t)bh * Tt + t) * Dd + d] = o;
      else if (sect == 1) Kd[((size_t)bh * Tt + t) * Dd + d] = o;
      else                VT[((size_t)bh * Dd + d) * Tt + t] = o;
    }
  }
}

// ---------------------------------------------------------------------------
// Flash attention: one wave per (b,h,16-row Q tile). K-tiles of 32.
// Q,K: [B,H,T,D] bf16; VT: [B,H,D,T] bf16; O: [B,H,T,D] bf16.
// ---------------------------------------------------------------------------
__global__ __launch_bounds__(64) void attn(
    const __hip_bfloat16* __restrict__ Q, const __hip_bfloat16* __restrict__ K,
    const __hip_bfloat16* __restrict__ VT, __hip_bfloat16* __restrict__ O) {
  const int lane = threadIdx.x;
  const int l16 = lane & 15, quad = lane >> 4;
  const int q0 = blockIdx.x * 16;
  const int bh = blockIdx.z * Hh + blockIdx.y;

  const __hip_bfloat16* Qh = Q + (size_t)bh * Tt * Dd;
  const __hip_bfloat16* Kh = K + (size_t)bh * Tt * Dd;
  const __hip_bfloat16* Vh = VT + (size_t)bh * Dd * Tt;
  __hip_bfloat16* Oh = O + (size_t)bh * Tt * Dd;

  __shared__ __align__(16) __hip_bfloat16 pbuf[16 * 32];

  const bf16x8 qf0 = ldg8(Qh + (size_t)(q0 + l16) * Dd + quad * 8);
  const bf16x8 qf1 = ldg8(Qh + (size_t)(q0 + l16) * Dd + 32 + quad * 8);

  f32x4 o_acc[4] = {};
  float mrow[4] = {-INFINITY, -INFINITY, -INFINITY, -INFINITY};
  float lrow[4] = {0.f, 0.f, 0.f, 0.f};

  const float SC = 0.18033688011112042f;  // (1/sqrt(64)) * log2(e)

  for (int k0 = 0; k0 < q0 + 16; k0 += 32) {
    f32x4 s0, s1;
    {
      const __hip_bfloat16* kr = Kh + (size_t)(k0 + l16) * Dd + quad * 8;
      f32x4 z = {};
      z = MFMA16(qf0, ldg8(kr), z);
      s0 = MFMA16(qf1, ldg8(kr + 32), z);
    }
    {
      const __hip_bfloat16* kr = Kh + (size_t)(k0 + 16 + l16) * Dd + quad * 8;
      f32x4 z = {};
      z = MFMA16(qf0, ldg8(kr), z);
      s1 = MFMA16(qf1, ldg8(kr + 32), z);
    }

    float alpha[4];
#pragma unroll
    for (int r = 0; r < 4; ++r) {
      const int row = q0 + quad * 4 + r;
      float v0 = (k0 + l16 <= row) ? s0[r] * SC : -INFINITY;
      float v1 = (k0 + 16 + l16 <= row) ? s1[r] * SC : -INFINITY;
      float mx = fmaxf(v0, v1);
#pragma unroll
      for (int off = 1; off < 16; off <<= 1)
        mx = fmaxf(mx, __shfl_xor(mx, off, 64));
      const float mnew = fmaxf(mrow[r], mx);
      alpha[r] = exp2f(mrow[r] - mnew);
      const float p0 = exp2f(v0 - mnew);
      const float p1 = exp2f(v1 - mnew);
      float rs = p0 + p1;
#pragma unroll
      for (int off = 1; off < 16; off <<= 1) rs += __shfl_xor(rs, off, 64);
      lrow[r] = lrow[r] * alpha[r] + rs;
      mrow[r] = mnew;
      pbuf[(quad * 4 + r) * 32 + l16] = __float2bfloat16(p0);
      pbuf[(quad * 4 + r) * 32 + 16 + l16] = __float2bfloat16(p1);
    }
#pragma unroll
    for (int dt = 0; dt < 4; ++dt) {
      f32x4 t = o_acc[dt];
#pragma unroll
      for (int r = 0; r < 4; ++r) t[r] *= alpha[r];
      o_acc[dt] = t;
    }
    __syncthreads();
    const bf16x8 pf = ldg8(pbuf + l16 * 32 + quad * 8);
#pragma unroll
    for (int dt = 0; dt < 4; ++dt) {
      bf16x8 vf = ldg8(Vh + (size_t)(dt * 16 + l16) * Tt + k0 + quad * 8);
      o_acc[dt] = MFMA16(pf, vf, o_acc[dt]);
    }
    __syncthreads();
  }

#pragma unroll
  for (int dt = 0; dt < 4; ++dt)
#pragma unroll
    for (int r = 0; r < 4; ++r) {
      const float val = o_acc[dt][r] / lrow[r];
      Oh[(size_t)(q0 + quad * 4 + r) * Dd + dt * 16 + l16] = __float2bfloat16(val);
    }
}

// ---------------------------------------------------------------------------
// Proj GEMM: y(f32)[4096,1024] = O([B,H,T,D] bf16, head-permuted) @ WT([1024,1024] bf16) + b(f32)
// ---------------------------------------------------------------------------
__global__ __launch_bounds__(256) void proj_gemm(
    const __hip_bfloat16* __restrict__ O, const __hip_bfloat16* __restrict__ WT,
    const float* __restrict__ bias, float* __restrict__ out) {
  const int wave = threadIdx.x >> 6;
  const int lane = threadIdx.x & 63;
  const int l16 = lane & 15, quad = lane >> 4;
  const int m0 = blockIdx.y * 64 + wave * 16;
  const int n0 = blockIdx.x * 64;

  const int m = m0 + l16;
  const int b = m >> 11, t = m & 2047;

  f32x4 acc[4] = {};
#pragma unroll 4
  for (int k0 = 0; k0 < Cc; k0 += 32) {
    const int c = k0 + quad * 8;  // channel = h*64 + d, 8 contiguous within a head
    const int h = c >> 6, d = c & 63;
    bf16x8 af = ldg8(O + ((size_t)(b * Hh + h) * Tt + t) * Dd + d);
#pragma unroll
    for (int cf = 0; cf < 4; ++cf) {
      bf16x8 bf = ldg8(WT + (size_t)(n0 + cf * 16 + l16) * Cc + k0 + quad * 8);
      acc[cf] = MFMA16(af, bf, acc[cf]);
    }
  }
#pragma unroll
  for (int cf = 0; cf < 4; ++cf) {
    const int n = n0 + cf * 16 + l16;
    const float bv = bias[n];
#pragma unroll
    for (int r = 0; r < 4; ++r)
      out[(size_t)(m0 + quad * 4 + r) * Cc + n] = acc[cf][r] + bv;
  }
}

// ---------------------------------------------------------------------------
extern "C" void kernel_launch(void* const* d_in, const int* in_sizes, int n_in,
                              void* d_out, int out_size, void* d_ws, size_t ws_size,
                              hipStream_t stream) {
  const float* x      = (const float*)d_in[0];
  const float* W_qkv  = (const float*)d_in[1];
  const float* b_qkv  = (const float*)d_in[2];
  const float* W_proj = (const float*)d_in[3];
  const float* b_proj = (const float*)d_in[4];
  float* out = (float*)d_out;

  __hip_bfloat16* ws = (__hip_bfloat16*)d_ws;
  const size_t NBHTD = (size_t)Bb * Hh * Tt * Dd;  // 4,194,304
  __hip_bfloat16* Qw  = ws;
  __hip_bfloat16* Kw  = ws + NBHTD;
  __hip_bfloat16* VTw = ws + 2 * NBHTD;
  __hip_bfloat16* Ow  = ws + 3 * NBHTD;
  __hip_bfloat16* xb  = ws + 4 * NBHTD;                  // [4096,1024]
  __hip_bfloat16* WTqkv  = xb + NBHTD;                   // [3072,1024]
  __hip_bfloat16* WTproj = WTqkv + (size_t)3 * Cc * Cc;  // [1024,1024]

  cvt_f32_bf16<<<dim3(4096), dim3(256), 0, stream>>>(x, xb, Bb * Tt * Cc);
  transpose_cvt<<<dim3(96, 32), dim3(32, 8), 0, stream>>>(W_qkv, WTqkv, Cc, 3 * Cc);
  transpose_cvt<<<dim3(32, 32), dim3(32, 8), 0, stream>>>(W_proj, WTproj, Cc, Cc);
  qkv_gemm<<<dim3(48, 64), 256, 0, stream>>>(xb, WTqkv, b_qkv, Qw, Kw, VTw);
  attn<<<dim3(Tt / 16, Hh, Bb), 64, 0, stream>>>(Qw, Kw, VTw, Ow);
  proj_gemm<<<dim3(16, 64), 256, 0, stream>>>(Ow, WTproj, b_proj, out);
}

// Round 3
// 502.264 us; speedup vs baseline: 1.2009x; 1.2009x over previous
//
#include <hip/hip_runtime.h>
#include <hip/hip_bf16.h>

// Problem: B=2, T=2048, C=1024, H=16, D=64. Tensors stored f32; compute bf16 MFMA.
#define Bb 2
#define Tt 2048
#define Cc 1024
#define Hh 16
#define Dd 64

typedef __bf16 bf16x8 __attribute__((ext_vector_type(8)));
typedef float f32x4 __attribute__((ext_vector_type(4)));

#define MFMA16(a, b, c) __builtin_amdgcn_mfma_f32_16x16x32_bf16((a), (b), (c), 0, 0, 0)

__device__ __forceinline__ bf16x8 ldg8(const __hip_bfloat16* p) {
  return *reinterpret_cast<const bf16x8*>(p);
}

// ---------------------------------------------------------------------------
// f32 -> bf16 elementwise cast (n divisible by 1024)
// ---------------------------------------------------------------------------
__global__ __launch_bounds__(256) void cvt_f32_bf16(
    const float* __restrict__ in, __hip_bfloat16* __restrict__ out, int n) {
  const int i = (blockIdx.x * 256 + threadIdx.x) * 4;
  if (i + 3 < n) {
    const float4 v = *reinterpret_cast<const float4*>(in + i);
    out[i + 0] = __float2bfloat16(v.x);
    out[i + 1] = __float2bfloat16(v.y);
    out[i + 2] = __float2bfloat16(v.z);
    out[i + 3] = __float2bfloat16(v.w);
  }
}

// ---------------------------------------------------------------------------
// Transpose+cast: in f32 [R][Cn] row-major -> out bf16 [Cn][R]
// ---------------------------------------------------------------------------
__global__ __launch_bounds__(256) void transpose_cvt(
    const float* __restrict__ in, __hip_bfloat16* __restrict__ out,
    int R, int Cn) {
  __shared__ float tile[32][33];
  const int c0 = blockIdx.x * 32, r0 = blockIdx.y * 32;
  const int tx = threadIdx.x, ty = threadIdx.y;  // block (32,8)
#pragma unroll
  for (int i = 0; i < 32; i += 8)
    tile[ty + i][tx] = in[(size_t)(r0 + ty + i) * Cn + c0 + tx];
  __syncthreads();
#pragma unroll
  for (int i = 0; i < 32; i += 8)
    out[(size_t)(c0 + ty + i) * R + r0 + tx] = __float2bfloat16(tile[tx][ty + i]);
}

// ---------------------------------------------------------------------------
// QKV GEMM: xb[4096,1024](bf16) @ WT([3072,1024] bf16) + b(f32)
//   -> Q,K [B,H,T,D] bf16, V^T [B,H,D,T] bf16
// ---------------------------------------------------------------------------
__global__ __launch_bounds__(256) void qkv_gemm(
    const __hip_bfloat16* __restrict__ x, const __hip_bfloat16* __restrict__ WT,
    const float* __restrict__ bias,
    __hip_bfloat16* __restrict__ Q, __hip_bfloat16* __restrict__ Kd,
    __hip_bfloat16* __restrict__ VT) {
  const int wave = threadIdx.x >> 6;
  const int lane = threadIdx.x & 63;
  const int l16 = lane & 15, quad = lane >> 4;
  const int m0 = blockIdx.y * 64 + wave * 16;
  const int n0 = blockIdx.x * 64;

  f32x4 acc[4] = {};
  const __hip_bfloat16* arow = x + (size_t)(m0 + l16) * Cc + quad * 8;
#pragma unroll 4
  for (int k0 = 0; k0 < Cc; k0 += 32) {
    bf16x8 af = ldg8(arow + k0);
#pragma unroll
    for (int c = 0; c < 4; ++c) {
      bf16x8 bf = ldg8(WT + (size_t)(n0 + c * 16 + l16) * Cc + k0 + quad * 8);
      acc[c] = MFMA16(af, bf, acc[c]);
    }
  }

#pragma unroll
  for (int c = 0; c < 4; ++c) {
    const int n = n0 + c * 16 + l16;
    const float bv = bias[n];
    const int sect = n >> 10;  // 0=Q 1=K 2=V
    const int ch = n & 1023;
    const int h = ch >> 6, d = ch & 63;
#pragma unroll
    for (int r = 0; r < 4; ++r) {
      const int m = m0 + quad * 4 + r;
      const int b = m >> 11, t = m & 2047;
      const __hip_bfloat16 o = __float2bfloat16(acc[c][r] + bv);
      const int bh = b * Hh + h;
      if (sect == 0)      Q[((size_t)bh * Tt + t) * Dd + d] = o;
      else if (sect == 1) Kd[((size_t)bh * Tt + t) * Dd + d] = o;
      else                VT[((size_t)bh * Dd + d) * Tt + t] = o;
    }
  }
}

// ---------------------------------------------------------------------------
// Flash attention v2: block = 4 waves, 64 Q-rows/block (16/wave),
// K-tiles of 64 staged in LDS (shared by all 4 waves).
// Q,K: [B,H,T,D] bf16; VT: [B,H,D,T] bf16; O: [B,H,T,D] bf16.
// ---------------------------------------------------------------------------
__global__ __launch_bounds__(256) void attn(
    const __hip_bfloat16* __restrict__ Q, const __hip_bfloat16* __restrict__ K,
    const __hip_bfloat16* __restrict__ VT, __hip_bfloat16* __restrict__ O) {
  const int tid = threadIdx.x;
  const int wave = tid >> 6, lane = tid & 63;
  const int l16 = lane & 15, quad = lane >> 4;
  const int q0 = blockIdx.x * 64;
  const int q0w = q0 + wave * 16;
  const int bh = blockIdx.z * Hh + blockIdx.y;

  const __hip_bfloat16* Qh = Q + (size_t)bh * Tt * Dd;
  const __hip_bfloat16* Kh = K + (size_t)bh * Tt * Dd;
  const __hip_bfloat16* Vh = VT + (size_t)bh * Dd * Tt;
  __hip_bfloat16* Oh = O + (size_t)bh * Tt * Dd;

  // Padded stride 72 elems (144B = 36 banks): bank rotation -> <=2-way aliasing.
  __shared__ __align__(16) __hip_bfloat16 Kt[64 * 72];
  __shared__ __align__(16) __hip_bfloat16 Vt[64 * 72];
  __shared__ __align__(16) __hip_bfloat16 Pt[4][16 * 72];

  const bf16x8 qf0 = ldg8(Qh + (size_t)(q0w + l16) * Dd + quad * 8);
  const bf16x8 qf1 = ldg8(Qh + (size_t)(q0w + l16) * Dd + 32 + quad * 8);

  f32x4 o_acc[4] = {};
  float mrow[4] = {-INFINITY, -INFINITY, -INFINITY, -INFINITY};
  float lrow[4] = {0.f, 0.f, 0.f, 0.f};

  const float SC = 0.18033688011112042f;  // (1/sqrt(64)) * log2(e)

  const int skey = tid >> 3;       // 0..31
  const int sd = (tid & 7) * 8;    // 0,8,..,56

  for (int k0 = 0; k0 < q0 + 64; k0 += 64) {
    __syncthreads();  // all waves done reading previous Kt/Vt
    {
      // K-tile rows k0+skey(+32), all 64 d; Vt rows d=skey(+32), keys k0..k0+63.
      bf16x8 ka = ldg8(Kh + (size_t)(k0 + skey) * Dd + sd);
      bf16x8 kb = ldg8(Kh + (size_t)(k0 + 32 + skey) * Dd + sd);
      bf16x8 va = ldg8(Vh + (size_t)skey * Tt + k0 + sd);
      bf16x8 vb = ldg8(Vh + (size_t)(32 + skey) * Tt + k0 + sd);
      *reinterpret_cast<bf16x8*>(&Kt[skey * 72 + sd]) = ka;
      *reinterpret_cast<bf16x8*>(&Kt[(32 + skey) * 72 + sd]) = kb;
      *reinterpret_cast<bf16x8*>(&Vt[skey * 72 + sd]) = va;
      *reinterpret_cast<bf16x8*>(&Vt[(32 + skey) * 72 + sd]) = vb;
    }
    __syncthreads();

    // QK^T: S[16 q x 64 keys] = 4 column tiles of 16.
    f32x4 s[4];
#pragma unroll
    for (int kt = 0; kt < 4; ++kt) {
      const __hip_bfloat16* kr = &Kt[(kt * 16 + l16) * 72 + quad * 8];
      f32x4 z = {};
      z = MFMA16(qf0, ldg8(kr), z);
      s[kt] = MFMA16(qf1, ldg8(kr + 32), z);
    }

    float alpha[4];
#pragma unroll
    for (int r = 0; r < 4; ++r) {
      const int row = q0w + quad * 4 + r;
      float v0 = (k0 + l16 <= row)      ? s[0][r] * SC : -INFINITY;
      float v1 = (k0 + 16 + l16 <= row) ? s[1][r] * SC : -INFINITY;
      float v2 = (k0 + 32 + l16 <= row) ? s[2][r] * SC : -INFINITY;
      float v3 = (k0 + 48 + l16 <= row) ? s[3][r] * SC : -INFINITY;
      float mx = fmaxf(fmaxf(v0, v1), fmaxf(v2, v3));
#pragma unroll
      for (int off = 1; off < 16; off <<= 1)
        mx = fmaxf(mx, __shfl_xor(mx, off, 64));
      const float mnew = fmaxf(mrow[r], mx);
      alpha[r] = exp2f(mrow[r] - mnew);
      const float p0 = exp2f(v0 - mnew);
      const float p1 = exp2f(v1 - mnew);
      const float p2 = exp2f(v2 - mnew);
      const float p3 = exp2f(v3 - mnew);
      float rs = (p0 + p1) + (p2 + p3);
#pragma unroll
      for (int off = 1; off < 16; off <<= 1) rs += __shfl_xor(rs, off, 64);
      lrow[r] = lrow[r] * alpha[r] + rs;
      mrow[r] = mnew;
      __hip_bfloat16* pr = &Pt[wave][(quad * 4 + r) * 72 + l16];
      pr[0] = __float2bfloat16(p0);
      pr[16] = __float2bfloat16(p1);
      pr[32] = __float2bfloat16(p2);
      pr[48] = __float2bfloat16(p3);
    }
#pragma unroll
    for (int dt = 0; dt < 4; ++dt) {
      f32x4 t = o_acc[dt];
#pragma unroll
      for (int r = 0; r < 4; ++r) t[r] *= alpha[r];
      o_acc[dt] = t;
    }

    // PV: P[16 x 64] @ V[64 keys x 64 d]. Pt is wave-private (no barrier needed;
    // in-wave LDS RAW ordering handled by lgkmcnt).
    const bf16x8 pf0 = ldg8(&Pt[wave][l16 * 72 + quad * 8]);
    const bf16x8 pf1 = ldg8(&Pt[wave][l16 * 72 + 32 + quad * 8]);
#pragma unroll
    for (int dt = 0; dt < 4; ++dt) {
      o_acc[dt] = MFMA16(pf0, ldg8(&Vt[(dt * 16 + l16) * 72 + quad * 8]), o_acc[dt]);
      o_acc[dt] = MFMA16(pf1, ldg8(&Vt[(dt * 16 + l16) * 72 + 32 + quad * 8]), o_acc[dt]);
    }
  }

#pragma unroll
  for (int dt = 0; dt < 4; ++dt)
#pragma unroll
    for (int r = 0; r < 4; ++r) {
      const float val = o_acc[dt][r] / lrow[r];
      Oh[(size_t)(q0w + quad * 4 + r) * Dd + dt * 16 + l16] = __float2bfloat16(val);
    }
}

// ---------------------------------------------------------------------------
// Proj GEMM: y(f32)[4096,1024] = O([B,H,T,D] bf16) @ WT([1024,1024] bf16) + b(f32)
// ---------------------------------------------------------------------------
__global__ __launch_bounds__(256) void proj_gemm(
    const __hip_bfloat16* __restrict__ O, const __hip_bfloat16* __restrict__ WT,
    const float* __restrict__ bias, float* __restrict__ out) {
  const int wave = threadIdx.x >> 6;
  const int lane = threadIdx.x & 63;
  const int l16 = lane & 15, quad = lane >> 4;
  const int m0 = blockIdx.y * 64 + wave * 16;
  const int n0 = blockIdx.x * 64;

  const int m = m0 + l16;
  const int b = m >> 11, t = m & 2047;

  f32x4 acc[4] = {};
#pragma unroll 4
  for (int k0 = 0; k0 < Cc; k0 += 32) {
    const int c = k0 + quad * 8;
    const int h = c >> 6, d = c & 63;
    bf16x8 af = ldg8(O + ((size_t)(b * Hh + h) * Tt + t) * Dd + d);
#pragma unroll
    for (int cf = 0; cf < 4; ++cf) {
      bf16x8 bf = ldg8(WT + (size_t)(n0 + cf * 16 + l16) * Cc + k0 + quad * 8);
      acc[cf] = MFMA16(af, bf, acc[cf]);
    }
  }
#pragma unroll
  for (int cf = 0; cf < 4; ++cf) {
    const int n = n0 + cf * 16 + l16;
    const float bv = bias[n];
#pragma unroll
    for (int r = 0; r < 4; ++r)
      out[(size_t)(m0 + quad * 4 + r) * Cc + n] = acc[cf][r] + bv;
  }
}

// ---------------------------------------------------------------------------
extern "C" void kernel_launch(void* const* d_in, const int* in_sizes, int n_in,
                              void* d_out, int out_size, void* d_ws, size_t ws_size,
                              hipStream_t stream) {
  const float* x      = (const float*)d_in[0];
  const float* W_qkv  = (const float*)d_in[1];
  const float* b_qkv  = (const float*)d_in[2];
  const float* W_proj = (const float*)d_in[3];
  const float* b_proj = (const float*)d_in[4];
  float* out = (float*)d_out;

  __hip_bfloat16* ws = (__hip_bfloat16*)d_ws;
  const size_t NBHTD = (size_t)Bb * Hh * Tt * Dd;  // 4,194,304
  __hip_bfloat16* Qw  = ws;
  __hip_bfloat16* Kw  = ws + NBHTD;
  __hip_bfloat16* VTw = ws + 2 * NBHTD;
  __hip_bfloat16* Ow  = ws + 3 * NBHTD;
  __hip_bfloat16* xb  = ws + 4 * NBHTD;                  // [4096,1024]
  __hip_bfloat16* WTqkv  = xb + NBHTD;                   // [3072,1024]
  __hip_bfloat16* WTproj = WTqkv + (size_t)3 * Cc * Cc;  // [1024,1024]

  cvt_f32_bf16<<<dim3(4096), dim3(256), 0, stream>>>(x, xb, Bb * Tt * Cc);
  transpose_cvt<<<dim3(96, 32), dim3(32, 8), 0, stream>>>(W_qkv, WTqkv, Cc, 3 * Cc);
  transpose_cvt<<<dim3(32, 32), dim3(32, 8), 0, stream>>>(W_proj, WTproj, Cc, Cc);
  qkv_gemm<<<dim3(48, 64), 256, 0, stream>>>(xb, WTqkv, b_qkv, Qw, Kw, VTw);
  attn<<<dim3(Tt / 64, Hh, Bb), 256, 0, stream>>>(Qw, Kw, VTw, Ow);
  proj_gemm<<<dim3(16, 64), 256, 0, stream>>>(Ow, WTproj, b_proj, out);
}

// Round 4
// 276.668 us; speedup vs baseline: 2.1802x; 1.8154x over previous
//
#include <hip/hip_runtime.h>
#include <hip/hip_bf16.h>

// Problem: B=2, T=2048, C=1024, H=16, D=64. Tensors stored f32; compute bf16 MFMA.
#define Bb 2
#define Tt 2048
#define Cc 1024
#define Hh 16
#define Dd 64

typedef __bf16 bf16x8 __attribute__((ext_vector_type(8)));
typedef float f32x4 __attribute__((ext_vector_type(4)));

#define MFMA16(a, b, c) __builtin_amdgcn_mfma_f32_16x16x32_bf16((a), (b), (c), 0, 0, 0)

__device__ __forceinline__ bf16x8 ldg8(const __hip_bfloat16* p) {
  return *reinterpret_cast<const bf16x8*>(p);
}

// Async global->LDS, 16B per lane. LDS dest = wave-uniform base + lane*16.
__device__ __forceinline__ void load_lds16(const __hip_bfloat16* g, __hip_bfloat16* l) {
  __builtin_amdgcn_global_load_lds(
      (const __attribute__((address_space(1))) void*)g,
      (__attribute__((address_space(3))) void*)l, 16, 0, 0);
}

// ---------------------------------------------------------------------------
// f32 -> bf16 elementwise cast
// ---------------------------------------------------------------------------
__global__ __launch_bounds__(256) void cvt_f32_bf16(
    const float* __restrict__ in, __hip_bfloat16* __restrict__ out, int n) {
  const int i = (blockIdx.x * 256 + threadIdx.x) * 4;
  if (i + 3 < n) {
    const float4 v = *reinterpret_cast<const float4*>(in + i);
    out[i + 0] = __float2bfloat16(v.x);
    out[i + 1] = __float2bfloat16(v.y);
    out[i + 2] = __float2bfloat16(v.z);
    out[i + 3] = __float2bfloat16(v.w);
  }
}

// ---------------------------------------------------------------------------
// Transpose+cast: in f32 [R][Cn] row-major -> out bf16 [Cn][R]
// ---------------------------------------------------------------------------
__global__ __launch_bounds__(256) void transpose_cvt(
    const float* __restrict__ in, __hip_bfloat16* __restrict__ out,
    int R, int Cn) {
  __shared__ float tile[32][33];
  const int c0 = blockIdx.x * 32, r0 = blockIdx.y * 32;
  const int tx = threadIdx.x, ty = threadIdx.y;  // block (32,8)
#pragma unroll
  for (int i = 0; i < 32; i += 8)
    tile[ty + i][tx] = in[(size_t)(r0 + ty + i) * Cn + c0 + tx];
  __syncthreads();
#pragma unroll
  for (int i = 0; i < 32; i += 8)
    out[(size_t)(c0 + ty + i) * R + r0 + tx] = __float2bfloat16(tile[tx][ty + i]);
}

// ---------------------------------------------------------------------------
// QKV GEMM (m97 structure): xb[4096,1024] @ WT[3072,1024]^T + b
//   -> Q,K [B,H,T,D] bf16, V^T [B,H,D,T] bf16
// 128x128 block tile, 4 waves 2x2, BK=32, global_load_lds staging.
// ---------------------------------------------------------------------------
__global__ __launch_bounds__(256) void qkv_gemm(
    const __hip_bfloat16* __restrict__ x, const __hip_bfloat16* __restrict__ WT,
    const float* __restrict__ bias,
    __hip_bfloat16* __restrict__ Q, __hip_bfloat16* __restrict__ Kd,
    __hip_bfloat16* __restrict__ VT) {
  __shared__ __hip_bfloat16 As[128 * 32];
  __shared__ __hip_bfloat16 Bs[128 * 32];
  const int tid = threadIdx.x;
  const int wave = tid >> 6, lane = tid & 63;
  const int l16 = lane & 15, quad = lane >> 4;
  const int m0 = blockIdx.y * 128, n0 = blockIdx.x * 128;
  const int wm = (wave >> 1) * 64, wn = (wave & 1) * 64;

  const int srow = wave * 32 + (lane >> 2);  // staging row (+16 for j=1)
  const int kseg = (lane & 3) * 8;

  f32x4 acc[4][4] = {};

  for (int k0 = 0; k0 < Cc; k0 += 32) {
    __syncthreads();  // previous iter's ds_reads done before overwrite
#pragma unroll
    for (int j = 0; j < 2; ++j) {
      load_lds16(x + (size_t)(m0 + srow + j * 16) * Cc + k0 + kseg,
                 As + (wave * 32 + j * 16) * 32);
      load_lds16(WT + (size_t)(n0 + srow + j * 16) * Cc + k0 + kseg,
                 Bs + (wave * 32 + j * 16) * 32);
    }
    __syncthreads();  // vmcnt(0) drain + barrier

    bf16x8 af[4], bfr[4];
#pragma unroll
    for (int i = 0; i < 4; ++i) {
      af[i] = ldg8(As + (wm + i * 16 + l16) * 32 + quad * 8);
      bfr[i] = ldg8(Bs + (wn + i * 16 + l16) * 32 + quad * 8);
    }
#pragma unroll
    for (int i = 0; i < 4; ++i)
#pragma unroll
      for (int jn = 0; jn < 4; ++jn)
        acc[i][jn] = MFMA16(af[i], bfr[jn], acc[i][jn]);
  }

  const int sect = n0 >> 10;  // uniform per block (128 | 1024): 0=Q 1=K 2=V
#pragma unroll
  for (int jn = 0; jn < 4; ++jn) {
    const int n = n0 + wn + jn * 16 + l16;
    const float bv = bias[n];
    const int ch = n & 1023;
    const int h = ch >> 6, d = ch & 63;
#pragma unroll
    for (int i = 0; i < 4; ++i) {
#pragma unroll
      for (int r = 0; r < 4; ++r) {
        const int m = m0 + wm + i * 16 + quad * 4 + r;
        const int b = m >> 11, t = m & 2047;
        const __hip_bfloat16 o = __float2bfloat16(acc[i][jn][r] + bv);
        const int bh = b * Hh + h;
        if (sect == 0)      Q[((size_t)bh * Tt + t) * Dd + d] = o;
        else if (sect == 1) Kd[((size_t)bh * Tt + t) * Dd + d] = o;
        else                VT[((size_t)bh * Dd + d) * Tt + t] = o;
      }
    }
  }
}

// ---------------------------------------------------------------------------
// Flash attention: block = 4 waves, 64 Q-rows/block (16/wave),
// K-tiles of 64 staged in LDS (shared by all 4 waves).
// ---------------------------------------------------------------------------
__global__ __launch_bounds__(256) void attn(
    const __hip_bfloat16* __restrict__ Q, const __hip_bfloat16* __restrict__ K,
    const __hip_bfloat16* __restrict__ VT, __hip_bfloat16* __restrict__ O) {
  const int tid = threadIdx.x;
  const int wave = tid >> 6, lane = tid & 63;
  const int l16 = lane & 15, quad = lane >> 4;
  const int q0 = blockIdx.x * 64;
  const int q0w = q0 + wave * 16;
  const int bh = blockIdx.z * Hh + blockIdx.y;

  const __hip_bfloat16* Qh = Q + (size_t)bh * Tt * Dd;
  const __hip_bfloat16* Kh = K + (size_t)bh * Tt * Dd;
  const __hip_bfloat16* Vh = VT + (size_t)bh * Dd * Tt;
  __hip_bfloat16* Oh = O + (size_t)bh * Tt * Dd;

  __shared__ __align__(16) __hip_bfloat16 Kt[64 * 72];
  __shared__ __align__(16) __hip_bfloat16 Vt[64 * 72];
  __shared__ __align__(16) __hip_bfloat16 Pt[4][16 * 72];

  const bf16x8 qf0 = ldg8(Qh + (size_t)(q0w + l16) * Dd + quad * 8);
  const bf16x8 qf1 = ldg8(Qh + (size_t)(q0w + l16) * Dd + 32 + quad * 8);

  f32x4 o_acc[4] = {};
  float mrow[4] = {-INFINITY, -INFINITY, -INFINITY, -INFINITY};
  float lrow[4] = {0.f, 0.f, 0.f, 0.f};

  const float SC = 0.18033688011112042f;  // (1/sqrt(64)) * log2(e)

  const int skey = tid >> 3;     // 0..31
  const int sd = (tid & 7) * 8;  // 0,8,..,56

  for (int k0 = 0; k0 < q0 + 64; k0 += 64) {
    __syncthreads();
    {
      bf16x8 ka = ldg8(Kh + (size_t)(k0 + skey) * Dd + sd);
      bf16x8 kb = ldg8(Kh + (size_t)(k0 + 32 + skey) * Dd + sd);
      bf16x8 va = ldg8(Vh + (size_t)skey * Tt + k0 + sd);
      bf16x8 vb = ldg8(Vh + (size_t)(32 + skey) * Tt + k0 + sd);
      *reinterpret_cast<bf16x8*>(&Kt[skey * 72 + sd]) = ka;
      *reinterpret_cast<bf16x8*>(&Kt[(32 + skey) * 72 + sd]) = kb;
      *reinterpret_cast<bf16x8*>(&Vt[skey * 72 + sd]) = va;
      *reinterpret_cast<bf16x8*>(&Vt[(32 + skey) * 72 + sd]) = vb;
    }
    __syncthreads();

    f32x4 s[4];
#pragma unroll
    for (int kt = 0; kt < 4; ++kt) {
      const __hip_bfloat16* kr = &Kt[(kt * 16 + l16) * 72 + quad * 8];
      f32x4 z = {};
      z = MFMA16(qf0, ldg8(kr), z);
      s[kt] = MFMA16(qf1, ldg8(kr + 32), z);
    }

    float alpha[4];
#pragma unroll
    for (int r = 0; r < 4; ++r) {
      const int row = q0w + quad * 4 + r;
      float v0 = (k0 + l16 <= row)      ? s[0][r] * SC : -INFINITY;
      float v1 = (k0 + 16 + l16 <= row) ? s[1][r] * SC : -INFINITY;
      float v2 = (k0 + 32 + l16 <= row) ? s[2][r] * SC : -INFINITY;
      float v3 = (k0 + 48 + l16 <= row) ? s[3][r] * SC : -INFINITY;
      float mx = fmaxf(fmaxf(v0, v1), fmaxf(v2, v3));
#pragma unroll
      for (int off = 1; off < 16; off <<= 1)
        mx = fmaxf(mx, __shfl_xor(mx, off, 64));
      const float mnew = fmaxf(mrow[r], mx);
      alpha[r] = exp2f(mrow[r] - mnew);
      const float p0 = exp2f(v0 - mnew);
      const float p1 = exp2f(v1 - mnew);
      const float p2 = exp2f(v2 - mnew);
      const float p3 = exp2f(v3 - mnew);
      float rs = (p0 + p1) + (p2 + p3);
#pragma unroll
      for (int off = 1; off < 16; off <<= 1) rs += __shfl_xor(rs, off, 64);
      lrow[r] = lrow[r] * alpha[r] + rs;
      mrow[r] = mnew;
      __hip_bfloat16* pr = &Pt[wave][(quad * 4 + r) * 72 + l16];
      pr[0] = __float2bfloat16(p0);
      pr[16] = __float2bfloat16(p1);
      pr[32] = __float2bfloat16(p2);
      pr[48] = __float2bfloat16(p3);
    }
#pragma unroll
    for (int dt = 0; dt < 4; ++dt) {
      f32x4 t = o_acc[dt];
#pragma unroll
      for (int r = 0; r < 4; ++r) t[r] *= alpha[r];
      o_acc[dt] = t;
    }

    const bf16x8 pf0 = ldg8(&Pt[wave][l16 * 72 + quad * 8]);
    const bf16x8 pf1 = ldg8(&Pt[wave][l16 * 72 + 32 + quad * 8]);
#pragma unroll
    for (int dt = 0; dt < 4; ++dt) {
      o_acc[dt] = MFMA16(pf0, ldg8(&Vt[(dt * 16 + l16) * 72 + quad * 8]), o_acc[dt]);
      o_acc[dt] = MFMA16(pf1, ldg8(&Vt[(dt * 16 + l16) * 72 + 32 + quad * 8]), o_acc[dt]);
    }
  }

#pragma unroll
  for (int dt = 0; dt < 4; ++dt)
#pragma unroll
    for (int r = 0; r < 4; ++r) {
      const float val = o_acc[dt][r] / lrow[r];
      Oh[(size_t)(q0w + quad * 4 + r) * Dd + dt * 16 + l16] = __float2bfloat16(val);
    }
}

// ---------------------------------------------------------------------------
// Proj GEMM (m97 structure): y(f32)[4096,1024] = O([B,H,T,D]) @ WT[1024,1024]^T + b
// ---------------------------------------------------------------------------
__global__ __launch_bounds__(256) void proj_gemm(
    const __hip_bfloat16* __restrict__ O, const __hip_bfloat16* __restrict__ WT,
    const float* __restrict__ bias, float* __restrict__ out) {
  __shared__ __hip_bfloat16 As[128 * 32];
  __shared__ __hip_bfloat16 Bs[128 * 32];
  const int tid = threadIdx.x;
  const int wave = tid >> 6, lane = tid & 63;
  const int l16 = lane & 15, quad = lane >> 4;
  const int m0 = blockIdx.y * 128, n0 = blockIdx.x * 128;
  const int wm = (wave >> 1) * 64, wn = (wave & 1) * 64;

  const int srow = wave * 32 + (lane >> 2);
  const int kseg = (lane & 3) * 8;

  f32x4 acc[4][4] = {};

  for (int k0 = 0; k0 < Cc; k0 += 32) {
    const int k = k0 + kseg;          // channel = h*64+d; 8-seg never crosses a head
    const int h = k >> 6, d = k & 63;
    __syncthreads();
#pragma unroll
    for (int j = 0; j < 2; ++j) {
      const int m = m0 + srow + j * 16;
      const int b = m >> 11, t = m & 2047;
      load_lds16(O + ((size_t)(b * Hh + h) * Tt + t) * Dd + d,
                 As + (wave * 32 + j * 16) * 32);
      load_lds16(WT + (size_t)(n0 + srow + j * 16) * Cc + k0 + kseg,
                 Bs + (wave * 32 + j * 16) * 32);
    }
    __syncthreads();

    bf16x8 af[4], bfr[4];
#pragma unroll
    for (int i = 0; i < 4; ++i) {
      af[i] = ldg8(As + (wm + i * 16 + l16) * 32 + quad * 8);
      bfr[i] = ldg8(Bs + (wn + i * 16 + l16) * 32 + quad * 8);
    }
#pragma unroll
    for (int i = 0; i < 4; ++i)
#pragma unroll
      for (int jn = 0; jn < 4; ++jn)
        acc[i][jn] = MFMA16(af[i], bfr[jn], acc[i][jn]);
  }

#pragma unroll
  for (int jn = 0; jn < 4; ++jn) {
    const int n = n0 + wn + jn * 16 + l16;
    const float bv = bias[n];
#pragma unroll
    for (int i = 0; i < 4; ++i)
#pragma unroll
      for (int r = 0; r < 4; ++r) {
        const int m = m0 + wm + i * 16 + quad * 4 + r;
        out[(size_t)m * Cc + n] = acc[i][jn][r] + bv;
      }
  }
}

// ---------------------------------------------------------------------------
extern "C" void kernel_launch(void* const* d_in, const int* in_sizes, int n_in,
                              void* d_out, int out_size, void* d_ws, size_t ws_size,
                              hipStream_t stream) {
  const float* x      = (const float*)d_in[0];
  const float* W_qkv  = (const float*)d_in[1];
  const float* b_qkv  = (const float*)d_in[2];
  const float* W_proj = (const float*)d_in[3];
  const float* b_proj = (const float*)d_in[4];
  float* out = (float*)d_out;

  __hip_bfloat16* ws = (__hip_bfloat16*)d_ws;
  const size_t NBHTD = (size_t)Bb * Hh * Tt * Dd;  // 4,194,304
  __hip_bfloat16* Qw  = ws;
  __hip_bfloat16* Kw  = ws + NBHTD;
  __hip_bfloat16* VTw = ws + 2 * NBHTD;
  __hip_bfloat16* Ow  = ws + 3 * NBHTD;
  __hip_bfloat16* xb  = ws + 4 * NBHTD;                  // [4096,1024]
  __hip_bfloat16* WTqkv  = xb + NBHTD;                   // [3072,1024]
  __hip_bfloat16* WTproj = WTqkv + (size_t)3 * Cc * Cc;  // [1024,1024]

  cvt_f32_bf16<<<dim3(4096), dim3(256), 0, stream>>>(x, xb, Bb * Tt * Cc);
  transpose_cvt<<<dim3(96, 32), dim3(32, 8), 0, stream>>>(W_qkv, WTqkv, Cc, 3 * Cc);
  transpose_cvt<<<dim3(32, 32), dim3(32, 8), 0, stream>>>(W_proj, WTproj, Cc, Cc);
  qkv_gemm<<<dim3(24, 32), 256, 0, stream>>>(xb, WTqkv, b_qkv, Qw, Kw, VTw);
  attn<<<dim3(Tt / 64, Hh, Bb), 256, 0, stream>>>(Qw, Kw, VTw, Ow);
  proj_gemm<<<dim3(8, 32), 256, 0, stream>>>(Ow, WTproj, b_proj, out);
}

// Round 5
// 238.478 us; speedup vs baseline: 2.5293x; 1.1601x over previous
//
#include <hip/hip_runtime.h>
#include <hip/hip_bf16.h>

// Problem: B=2, T=2048, C=1024, H=16, D=64. Tensors stored f32; compute bf16 MFMA.
#define Bb 2
#define Tt 2048
#define Cc 1024
#define Hh 16
#define Dd 64

typedef __bf16 bf16x8 __attribute__((ext_vector_type(8)));
typedef __bf16 bf16x4 __attribute__((ext_vector_type(4)));
typedef float f32x4 __attribute__((ext_vector_type(4)));

#define MFMA16(a, b, c) __builtin_amdgcn_mfma_f32_16x16x32_bf16((a), (b), (c), 0, 0, 0)

__device__ __forceinline__ bf16x8 ldg8(const __hip_bfloat16* p) {
  return *reinterpret_cast<const bf16x8*>(p);
}

// Async global->LDS, 16B per lane. LDS dest = wave-uniform base + lane*16.
__device__ __forceinline__ void load_lds16(const __hip_bfloat16* g, __hip_bfloat16* l) {
  __builtin_amdgcn_global_load_lds(
      (const __attribute__((address_space(1))) void*)g,
      (__attribute__((address_space(3))) void*)l, 16, 0, 0);
}

// ---------------------------------------------------------------------------
// f32 -> bf16 elementwise cast
// ---------------------------------------------------------------------------
__global__ __launch_bounds__(256) void cvt_f32_bf16(
    const float* __restrict__ in, __hip_bfloat16* __restrict__ out, int n) {
  const int i = (blockIdx.x * 256 + threadIdx.x) * 4;
  if (i + 3 < n) {
    const float4 v = *reinterpret_cast<const float4*>(in + i);
    out[i + 0] = __float2bfloat16(v.x);
    out[i + 1] = __float2bfloat16(v.y);
    out[i + 2] = __float2bfloat16(v.z);
    out[i + 3] = __float2bfloat16(v.w);
  }
}

// ---------------------------------------------------------------------------
// Transpose+cast: in f32 [R][Cn] row-major -> out bf16 [Cn][R]
// ---------------------------------------------------------------------------
__global__ __launch_bounds__(256) void transpose_cvt(
    const float* __restrict__ in, __hip_bfloat16* __restrict__ out,
    int R, int Cn) {
  __shared__ float tile[32][33];
  const int c0 = blockIdx.x * 32, r0 = blockIdx.y * 32;
  const int tx = threadIdx.x, ty = threadIdx.y;  // block (32,8)
#pragma unroll
  for (int i = 0; i < 32; i += 8)
    tile[ty + i][tx] = in[(size_t)(r0 + ty + i) * Cn + c0 + tx];
  __syncthreads();
#pragma unroll
  for (int i = 0; i < 32; i += 8)
    out[(size_t)(c0 + ty + i) * R + r0 + tx] = __float2bfloat16(tile[tx][ty + i]);
}

// ---------------------------------------------------------------------------
// QKV GEMM (m97 structure): xb[4096,1024] @ WT[3072,1024]^T + b
// ---------------------------------------------------------------------------
__global__ __launch_bounds__(256) void qkv_gemm(
    const __hip_bfloat16* __restrict__ x, const __hip_bfloat16* __restrict__ WT,
    const float* __restrict__ bias,
    __hip_bfloat16* __restrict__ Q, __hip_bfloat16* __restrict__ Kd,
    __hip_bfloat16* __restrict__ VT) {
  __shared__ __hip_bfloat16 As[128 * 32];
  __shared__ __hip_bfloat16 Bs[128 * 32];
  const int tid = threadIdx.x;
  const int wave = tid >> 6, lane = tid & 63;
  const int l16 = lane & 15, quad = lane >> 4;
  const int m0 = blockIdx.y * 128, n0 = blockIdx.x * 128;
  const int wm = (wave >> 1) * 64, wn = (wave & 1) * 64;

  const int srow = wave * 32 + (lane >> 2);
  const int kseg = (lane & 3) * 8;

  f32x4 acc[4][4] = {};

  for (int k0 = 0; k0 < Cc; k0 += 32) {
    __syncthreads();
#pragma unroll
    for (int j = 0; j < 2; ++j) {
      load_lds16(x + (size_t)(m0 + srow + j * 16) * Cc + k0 + kseg,
                 As + (wave * 32 + j * 16) * 32);
      load_lds16(WT + (size_t)(n0 + srow + j * 16) * Cc + k0 + kseg,
                 Bs + (wave * 32 + j * 16) * 32);
    }
    __syncthreads();

    bf16x8 af[4], bfr[4];
#pragma unroll
    for (int i = 0; i < 4; ++i) {
      af[i] = ldg8(As + (wm + i * 16 + l16) * 32 + quad * 8);
      bfr[i] = ldg8(Bs + (wn + i * 16 + l16) * 32 + quad * 8);
    }
#pragma unroll
    for (int i = 0; i < 4; ++i)
#pragma unroll
      for (int jn = 0; jn < 4; ++jn)
        acc[i][jn] = MFMA16(af[i], bfr[jn], acc[i][jn]);
  }

  const int sect = n0 >> 10;  // 0=Q 1=K 2=V (uniform per block)
#pragma unroll
  for (int jn = 0; jn < 4; ++jn) {
    const int n = n0 + wn + jn * 16 + l16;
    const float bv = bias[n];
    const int ch = n & 1023;
    const int h = ch >> 6, d = ch & 63;
#pragma unroll
    for (int i = 0; i < 4; ++i) {
#pragma unroll
      for (int r = 0; r < 4; ++r) {
        const int m = m0 + wm + i * 16 + quad * 4 + r;
        const int b = m >> 11, t = m & 2047;
        const __hip_bfloat16 o = __float2bfloat16(acc[i][jn][r] + bv);
        const int bh = b * Hh + h;
        if (sect == 0)      Q[((size_t)bh * Tt + t) * Dd + d] = o;
        else if (sect == 1) Kd[((size_t)bh * Tt + t) * Dd + d] = o;
        else                VT[((size_t)bh * Dd + d) * Tt + t] = o;
      }
    }
  }
}

// ---------------------------------------------------------------------------
// Flash attention v3: transposed-S orientation.
// Block = 4 waves, 64 Q-rows (16/wave), K-tiles of 64 in LDS.
// Per lane: softmax state for ONE q-row (q = q0w + l16); keys spread over
// quads+regs -> max/sum need only 2 cross-lane shuffles each.
// S^T = K·Q^T (swap MFMA operands; Q frag registers unchanged).
// O^T = V^T·P^T via MFMA16(vf, pf) -> output col = l16 = q matches state.
// ---------------------------------------------------------------------------
__global__ __launch_bounds__(256) void attn(
    const __hip_bfloat16* __restrict__ Q, const __hip_bfloat16* __restrict__ K,
    const __hip_bfloat16* __restrict__ VT, __hip_bfloat16* __restrict__ O) {
  const int tid = threadIdx.x;
  const int wave = tid >> 6, lane = tid & 63;
  const int l16 = lane & 15, quad = lane >> 4;
  const int q0 = blockIdx.x * 64;
  const int q0w = q0 + wave * 16;
  const int qrow = q0w + l16;
  const int bh = blockIdx.z * Hh + blockIdx.y;

  const __hip_bfloat16* Qh = Q + (size_t)bh * Tt * Dd;
  const __hip_bfloat16* Kh = K + (size_t)bh * Tt * Dd;
  const __hip_bfloat16* Vh = VT + (size_t)bh * Dd * Tt;
  __hip_bfloat16* Oh = O + (size_t)bh * Tt * Dd;

  __shared__ __align__(16) __bf16 Kt[64 * 72];
  __shared__ __align__(16) __bf16 Vt[64 * 72];
  __shared__ __align__(16) __bf16 Pt[4][16 * 72];

  const bf16x8 qf0 = ldg8(Qh + (size_t)qrow * Dd + quad * 8);
  const bf16x8 qf1 = ldg8(Qh + (size_t)qrow * Dd + 32 + quad * 8);

  f32x4 o_acc[4] = {};
  float m_s = -INFINITY, l_s = 0.f;

  const float SC = 0.18033688011112042f;  // (1/sqrt(64)) * log2(e)

  const int skey = tid >> 3;     // 0..31
  const int sd = (tid & 7) * 8;  // 0,8,..,56

  for (int k0 = 0; k0 < q0 + 64; k0 += 64) {
    __syncthreads();
    {
      bf16x8 ka = ldg8(Kh + (size_t)(k0 + skey) * Dd + sd);
      bf16x8 kb = ldg8(Kh + (size_t)(k0 + 32 + skey) * Dd + sd);
      bf16x8 va = ldg8(Vh + (size_t)skey * Tt + k0 + sd);
      bf16x8 vb = ldg8(Vh + (size_t)(32 + skey) * Tt + k0 + sd);
      *reinterpret_cast<bf16x8*>(&Kt[skey * 72 + sd]) = ka;
      *reinterpret_cast<bf16x8*>(&Kt[(32 + skey) * 72 + sd]) = kb;
      *reinterpret_cast<bf16x8*>(&Vt[skey * 72 + sd]) = va;
      *reinterpret_cast<bf16x8*>(&Vt[(32 + skey) * 72 + sd]) = vb;
    }
    __syncthreads();

    // S^T tiles: D[m=key(quad*4+r within kt*16)][n=q(l16)]
    f32x4 st[4];
#pragma unroll
    for (int kt = 0; kt < 4; ++kt) {
      const __bf16* kr = &Kt[(kt * 16 + l16) * 72 + quad * 8];
      f32x4 z = {};
      z = MFMA16(*reinterpret_cast<const bf16x8*>(kr), qf0, z);
      st[kt] = MFMA16(*reinterpret_cast<const bf16x8*>(kr + 32), qf1, z);
    }

    // Mask + scale, in-lane max over 16 values, 2-shuffle quad reduction.
    float v[16];
    float mx = -INFINITY;
#pragma unroll
    for (int kt = 0; kt < 4; ++kt)
#pragma unroll
      for (int r = 0; r < 4; ++r) {
        const int key = k0 + kt * 16 + quad * 4 + r;
        const float val = (key <= qrow) ? st[kt][r] * SC : -INFINITY;
        v[kt * 4 + r] = val;
        mx = fmaxf(mx, val);
      }
    mx = fmaxf(mx, __shfl_xor(mx, 16, 64));
    mx = fmaxf(mx, __shfl_xor(mx, 32, 64));
    const float mnew = fmaxf(m_s, mx);
    const float alpha = exp2f(m_s - mnew);
    m_s = mnew;

    // exp, in-lane sum, P -> LDS packed (4x ds_write_b64), 2-shuffle sum.
    float rs = 0.f;
#pragma unroll
    for (int kt = 0; kt < 4; ++kt) {
      bf16x4 pk;
#pragma unroll
      for (int r = 0; r < 4; ++r) {
        const float p = exp2f(v[kt * 4 + r] - mnew);
        rs += p;
        pk[r] = (__bf16)p;
      }
      *reinterpret_cast<bf16x4*>(&Pt[wave][l16 * 72 + kt * 16 + quad * 4]) = pk;
    }
    rs += __shfl_xor(rs, 16, 64);
    rs += __shfl_xor(rs, 32, 64);
    l_s = l_s * alpha + rs;

#pragma unroll
    for (int dt = 0; dt < 4; ++dt) o_acc[dt] *= alpha;

    // O^T += V^T·P^T : A = V^T frag (rows d), B = P frag (rows q).
    const bf16x8 pf0 = *reinterpret_cast<const bf16x8*>(&Pt[wave][l16 * 72 + quad * 8]);
    const bf16x8 pf1 = *reinterpret_cast<const bf16x8*>(&Pt[wave][l16 * 72 + 32 + quad * 8]);
#pragma unroll
    for (int dt = 0; dt < 4; ++dt) {
      const __bf16* vr = &Vt[(dt * 16 + l16) * 72];
      o_acc[dt] = MFMA16(*reinterpret_cast<const bf16x8*>(vr + quad * 8), pf0, o_acc[dt]);
      o_acc[dt] = MFMA16(*reinterpret_cast<const bf16x8*>(vr + 32 + quad * 8), pf1, o_acc[dt]);
    }
  }

  // o_acc[dt][r] = O[q=qrow][d=dt*16+quad*4+r]; packed 8B stores.
  const float inv = 1.f / l_s;
#pragma unroll
  for (int dt = 0; dt < 4; ++dt) {
    bf16x4 ov;
#pragma unroll
    for (int r = 0; r < 4; ++r) ov[r] = (__bf16)(o_acc[dt][r] * inv);
    *reinterpret_cast<bf16x4*>(&Oh[(size_t)qrow * Dd + dt * 16 + quad * 4]) = ov;
  }
}

// ---------------------------------------------------------------------------
// Proj GEMM (m97 structure): y(f32)[4096,1024] = O([B,H,T,D]) @ WT[1024,1024]^T + b
// ---------------------------------------------------------------------------
__global__ __launch_bounds__(256) void proj_gemm(
    const __hip_bfloat16* __restrict__ O, const __hip_bfloat16* __restrict__ WT,
    const float* __restrict__ bias, float* __restrict__ out) {
  __shared__ __hip_bfloat16 As[128 * 32];
  __shared__ __hip_bfloat16 Bs[128 * 32];
  const int tid = threadIdx.x;
  const int wave = tid >> 6, lane = tid & 63;
  const int l16 = lane & 15, quad = lane >> 4;
  const int m0 = blockIdx.y * 128, n0 = blockIdx.x * 128;
  const int wm = (wave >> 1) * 64, wn = (wave & 1) * 64;

  const int srow = wave * 32 + (lane >> 2);
  const int kseg = (lane & 3) * 8;

  f32x4 acc[4][4] = {};

  for (int k0 = 0; k0 < Cc; k0 += 32) {
    const int k = k0 + kseg;  // channel = h*64+d; 8-seg never crosses a head
    const int h = k >> 6, d = k & 63;
    __syncthreads();
#pragma unroll
    for (int j = 0; j < 2; ++j) {
      const int m = m0 + srow + j * 16;
      const int b = m >> 11, t = m & 2047;
      load_lds16(O + ((size_t)(b * Hh + h) * Tt + t) * Dd + d,
                 As + (wave * 32 + j * 16) * 32);
      load_lds16(WT + (size_t)(n0 + srow + j * 16) * Cc + k0 + kseg,
                 Bs + (wave * 32 + j * 16) * 32);
    }
    __syncthreads();

    bf16x8 af[4], bfr[4];
#pragma unroll
    for (int i = 0; i < 4; ++i) {
      af[i] = ldg8(As + (wm + i * 16 + l16) * 32 + quad * 8);
      bfr[i] = ldg8(Bs + (wn + i * 16 + l16) * 32 + quad * 8);
    }
#pragma unroll
    for (int i = 0; i < 4; ++i)
#pragma unroll
      for (int jn = 0; jn < 4; ++jn)
        acc[i][jn] = MFMA16(af[i], bfr[jn], acc[i][jn]);
  }

#pragma unroll
  for (int jn = 0; jn < 4; ++jn) {
    const int n = n0 + wn + jn * 16 + l16;
    const float bv = bias[n];
#pragma unroll
    for (int i = 0; i < 4; ++i)
#pragma unroll
      for (int r = 0; r < 4; ++r) {
        const int m = m0 + wm + i * 16 + quad * 4 + r;
        out[(size_t)m * Cc + n] = acc[i][jn][r] + bv;
      }
  }
}

// ---------------------------------------------------------------------------
extern "C" void kernel_launch(void* const* d_in, const int* in_sizes, int n_in,
                              void* d_out, int out_size, void* d_ws, size_t ws_size,
                              hipStream_t stream) {
  const float* x      = (const float*)d_in[0];
  const float* W_qkv  = (const float*)d_in[1];
  const float* b_qkv  = (const float*)d_in[2];
  const float* W_proj = (const float*)d_in[3];
  const float* b_proj = (const float*)d_in[4];
  float* out = (float*)d_out;

  __hip_bfloat16* ws = (__hip_bfloat16*)d_ws;
  const size_t NBHTD = (size_t)Bb * Hh * Tt * Dd;  // 4,194,304
  __hip_bfloat16* Qw  = ws;
  __hip_bfloat16* Kw  = ws + NBHTD;
  __hip_bfloat16* VTw = ws + 2 * NBHTD;
  __hip_bfloat16* Ow  = ws + 3 * NBHTD;
  __hip_bfloat16* xb  = ws + 4 * NBHTD;                  // [4096,1024]
  __hip_bfloat16* WTqkv  = xb + NBHTD;                   // [3072,1024]
  __hip_bfloat16* WTproj = WTqkv + (size_t)3 * Cc * Cc;  // [1024,1024]

  cvt_f32_bf16<<<dim3(4096), dim3(256), 0, stream>>>(x, xb, Bb * Tt * Cc);
  transpose_cvt<<<dim3(96, 32), dim3(32, 8), 0, stream>>>(W_qkv, WTqkv, Cc, 3 * Cc);
  transpose_cvt<<<dim3(32, 32), dim3(32, 8), 0, stream>>>(W_proj, WTproj, Cc, Cc);
  qkv_gemm<<<dim3(24, 32), 256, 0, stream>>>(xb, WTqkv, b_qkv, Qw, Kw, VTw);
  attn<<<dim3(Tt / 64, Hh, Bb), 256, 0, stream>>>(Qw, Kw, VTw, Ow);
  proj_gemm<<<dim3(8, 32), 256, 0, stream>>>(Ow, WTproj, b_proj, out);
}

// Round 6
// 207.849 us; speedup vs baseline: 2.9020x; 1.1474x over previous
//
#include <hip/hip_runtime.h>
#include <hip/hip_bf16.h>

// Problem: B=2, T=2048, C=1024, H=16, D=64. Tensors stored f32; compute bf16 MFMA.
#define Bb 2
#define Tt 2048
#define Cc 1024
#define Hh 16
#define Dd 64

typedef __bf16 bf16x8 __attribute__((ext_vector_type(8)));
typedef __bf16 bf16x4 __attribute__((ext_vector_type(4)));
typedef float f32x4 __attribute__((ext_vector_type(4)));

#define MFMA16(a, b, c) __builtin_amdgcn_mfma_f32_16x16x32_bf16((a), (b), (c), 0, 0, 0)

__device__ __forceinline__ bf16x8 ldg8(const __hip_bfloat16* p) {
  return *reinterpret_cast<const bf16x8*>(p);
}
__device__ __forceinline__ bf16x8 lds8(const __bf16* p) {
  return *reinterpret_cast<const bf16x8*>(p);
}

// Async global->LDS, 16B per lane. LDS dest = wave-uniform base + lane*16.
__device__ __forceinline__ void load_lds16(const __hip_bfloat16* g, __hip_bfloat16* l) {
  __builtin_amdgcn_global_load_lds(
      (const __attribute__((address_space(1))) void*)g,
      (__attribute__((address_space(3))) void*)l, 16, 0, 0);
}

// ---------------------------------------------------------------------------
// f32 -> bf16 elementwise cast
// ---------------------------------------------------------------------------
__global__ __launch_bounds__(256) void cvt_f32_bf16(
    const float* __restrict__ in, __hip_bfloat16* __restrict__ out, int n) {
  const int i = (blockIdx.x * 256 + threadIdx.x) * 4;
  if (i + 3 < n) {
    const float4 v = *reinterpret_cast<const float4*>(in + i);
    out[i + 0] = __float2bfloat16(v.x);
    out[i + 1] = __float2bfloat16(v.y);
    out[i + 2] = __float2bfloat16(v.z);
    out[i + 3] = __float2bfloat16(v.w);
  }
}

// ---------------------------------------------------------------------------
// Transpose+cast: in f32 [R][Cn] row-major -> out bf16 [Cn][R]
// ---------------------------------------------------------------------------
__global__ __launch_bounds__(256) void transpose_cvt(
    const float* __restrict__ in, __hip_bfloat16* __restrict__ out,
    int R, int Cn) {
  __shared__ float tile[32][33];
  const int c0 = blockIdx.x * 32, r0 = blockIdx.y * 32;
  const int tx = threadIdx.x, ty = threadIdx.y;  // block (32,8)
#pragma unroll
  for (int i = 0; i < 32; i += 8)
    tile[ty + i][tx] = in[(size_t)(r0 + ty + i) * Cn + c0 + tx];
  __syncthreads();
#pragma unroll
  for (int i = 0; i < 32; i += 8)
    out[(size_t)(c0 + ty + i) * R + r0 + tx] = __float2bfloat16(tile[tx][ty + i]);
}

// ---------------------------------------------------------------------------
// QKV GEMM (m97 structure): xb[4096,1024] @ WT[3072,1024]^T + b
// ---------------------------------------------------------------------------
__global__ __launch_bounds__(256) void qkv_gemm(
    const __hip_bfloat16* __restrict__ x, const __hip_bfloat16* __restrict__ WT,
    const float* __restrict__ bias,
    __hip_bfloat16* __restrict__ Q, __hip_bfloat16* __restrict__ Kd,
    __hip_bfloat16* __restrict__ VT) {
  __shared__ __hip_bfloat16 As[128 * 32];
  __shared__ __hip_bfloat16 Bs[128 * 32];
  const int tid = threadIdx.x;
  const int wave = tid >> 6, lane = tid & 63;
  const int l16 = lane & 15, quad = lane >> 4;
  const int m0 = blockIdx.y * 128, n0 = blockIdx.x * 128;
  const int wm = (wave >> 1) * 64, wn = (wave & 1) * 64;

  const int srow = wave * 32 + (lane >> 2);
  const int kseg = (lane & 3) * 8;

  f32x4 acc[4][4] = {};

  for (int k0 = 0; k0 < Cc; k0 += 32) {
    __syncthreads();
#pragma unroll
    for (int j = 0; j < 2; ++j) {
      load_lds16(x + (size_t)(m0 + srow + j * 16) * Cc + k0 + kseg,
                 As + (wave * 32 + j * 16) * 32);
      load_lds16(WT + (size_t)(n0 + srow + j * 16) * Cc + k0 + kseg,
                 Bs + (wave * 32 + j * 16) * 32);
    }
    __syncthreads();

    bf16x8 af[4], bfr[4];
#pragma unroll
    for (int i = 0; i < 4; ++i) {
      af[i] = ldg8(As + (wm + i * 16 + l16) * 32 + quad * 8);
      bfr[i] = ldg8(Bs + (wn + i * 16 + l16) * 32 + quad * 8);
    }
#pragma unroll
    for (int i = 0; i < 4; ++i)
#pragma unroll
      for (int jn = 0; jn < 4; ++jn)
        acc[i][jn] = MFMA16(af[i], bfr[jn], acc[i][jn]);
  }

  const int sect = n0 >> 10;  // 0=Q 1=K 2=V (uniform per block)
#pragma unroll
  for (int jn = 0; jn < 4; ++jn) {
    const int n = n0 + wn + jn * 16 + l16;
    const float bv = bias[n];
    const int ch = n & 1023;
    const int h = ch >> 6, d = ch & 63;
#pragma unroll
    for (int i = 0; i < 4; ++i) {
#pragma unroll
      for (int r = 0; r < 4; ++r) {
        const int m = m0 + wm + i * 16 + quad * 4 + r;
        const int b = m >> 11, t = m & 2047;
        const __hip_bfloat16 o = __float2bfloat16(acc[i][jn][r] + bv);
        const int bh = b * Hh + h;
        if (sect == 0)      Q[((size_t)bh * Tt + t) * Dd + d] = o;
        else if (sect == 1) Kd[((size_t)bh * Tt + t) * Dd + d] = o;
        else                VT[((size_t)bh * Dd + d) * Tt + t] = o;
      }
    }
  }
}

// ---------------------------------------------------------------------------
// Flash attention v4: transposed-S + causal pairing + register prefetch.
// Block = 4 waves; processes q-tiles {bx, 31-bx} (two phases) -> every block
// does exactly 33 K-iterations (uniform makespan, no straggler tail).
// Next K/V tile prefetched into registers before the compute barrier.
// ---------------------------------------------------------------------------
__global__ __launch_bounds__(256) void attn(
    const __hip_bfloat16* __restrict__ Q, const __hip_bfloat16* __restrict__ K,
    const __hip_bfloat16* __restrict__ VT, __hip_bfloat16* __restrict__ O) {
  const int tid = threadIdx.x;
  const int wave = tid >> 6, lane = tid & 63;
  const int l16 = lane & 15, quad = lane >> 4;
  const int bh = blockIdx.z * Hh + blockIdx.y;

  const __hip_bfloat16* Qh = Q + (size_t)bh * Tt * Dd;
  const __hip_bfloat16* Kh = K + (size_t)bh * Tt * Dd;
  const __hip_bfloat16* Vh = VT + (size_t)bh * Dd * Tt;
  __hip_bfloat16* Oh = O + (size_t)bh * Tt * Dd;

  __shared__ __align__(16) __bf16 Kt[64 * 72];
  __shared__ __align__(16) __bf16 Vt[64 * 72];
  __shared__ __align__(16) __bf16 Pt[4][16 * 72];

  const float SC = 0.18033688011112042f;  // (1/sqrt(64)) * log2(e)
  const int skey = tid >> 3;     // 0..31
  const int sd = (tid & 7) * 8;  // 0,8,..,56

  for (int phase = 0; phase < 2; ++phase) {
    const int qb = phase ? (Tt / 64 - 1) - blockIdx.x : blockIdx.x;
    const int q0 = qb * 64;
    const int qrow = q0 + wave * 16 + l16;

    const bf16x8 qf0 = ldg8(Qh + (size_t)qrow * Dd + quad * 8);
    const bf16x8 qf1 = ldg8(Qh + (size_t)qrow * Dd + 32 + quad * 8);

    f32x4 o_acc[4] = {};
    float m_s = -INFINITY, l_s = 0.f;

    const int nk = qb + 1;
    // Prologue prefetch (tile 0).
    bf16x8 ka = ldg8(Kh + (size_t)skey * Dd + sd);
    bf16x8 kb = ldg8(Kh + (size_t)(32 + skey) * Dd + sd);
    bf16x8 va = ldg8(Vh + (size_t)skey * Tt + sd);
    bf16x8 vb = ldg8(Vh + (size_t)(32 + skey) * Tt + sd);

    for (int kt0 = 0; kt0 < nk; ++kt0) {
      const int k0 = kt0 * 64;
      __syncthreads();  // all waves done reading previous Kt/Vt
      *reinterpret_cast<bf16x8*>(&Kt[skey * 72 + sd]) = ka;
      *reinterpret_cast<bf16x8*>(&Kt[(32 + skey) * 72 + sd]) = kb;
      *reinterpret_cast<bf16x8*>(&Vt[skey * 72 + sd]) = va;
      *reinterpret_cast<bf16x8*>(&Vt[(32 + skey) * 72 + sd]) = vb;
      if (kt0 + 1 < nk) {  // prefetch next tile; completes during compute
        const int k1 = k0 + 64;
        ka = ldg8(Kh + (size_t)(k1 + skey) * Dd + sd);
        kb = ldg8(Kh + (size_t)(k1 + 32 + skey) * Dd + sd);
        va = ldg8(Vh + (size_t)skey * Tt + k1 + sd);
        vb = ldg8(Vh + (size_t)(32 + skey) * Tt + k1 + sd);
      }
      __syncthreads();

      // S^T tiles: D[m=key(kt*16+quad*4+r)][n=q(l16)]
      f32x4 st[4];
#pragma unroll
      for (int kt = 0; kt < 4; ++kt) {
        const __bf16* kr = &Kt[(kt * 16 + l16) * 72 + quad * 8];
        f32x4 z = {};
        z = MFMA16(lds8(kr), qf0, z);
        st[kt] = MFMA16(lds8(kr + 32), qf1, z);
      }

      // Mask + scale; in-lane max over 16; 2-shuffle reduction.
      float v[16];
      float mx = -INFINITY;
#pragma unroll
      for (int kt = 0; kt < 4; ++kt)
#pragma unroll
        for (int r = 0; r < 4; ++r) {
          const int key = k0 + kt * 16 + quad * 4 + r;
          const float val = (key <= qrow) ? st[kt][r] * SC : -INFINITY;
          v[kt * 4 + r] = val;
          mx = fmaxf(mx, val);
        }
      mx = fmaxf(mx, __shfl_xor(mx, 16, 64));
      mx = fmaxf(mx, __shfl_xor(mx, 32, 64));
      const float mnew = fmaxf(m_s, mx);
      const float alpha = exp2f(m_s - mnew);
      m_s = mnew;

      float rs = 0.f;
#pragma unroll
      for (int kt = 0; kt < 4; ++kt) {
        bf16x4 pk;
#pragma unroll
        for (int r = 0; r < 4; ++r) {
          const float p = exp2f(v[kt * 4 + r] - mnew);
          rs += p;
          pk[r] = (__bf16)p;
        }
        *reinterpret_cast<bf16x4*>(&Pt[wave][l16 * 72 + kt * 16 + quad * 4]) = pk;
      }
      rs += __shfl_xor(rs, 16, 64);
      rs += __shfl_xor(rs, 32, 64);
      l_s = l_s * alpha + rs;

#pragma unroll
      for (int dt = 0; dt < 4; ++dt) o_acc[dt] *= alpha;

      // O^T += V^T·P^T (Pt wave-private; in-wave RAW via lgkmcnt).
      const bf16x8 pf0 = lds8(&Pt[wave][l16 * 72 + quad * 8]);
      const bf16x8 pf1 = lds8(&Pt[wave][l16 * 72 + 32 + quad * 8]);
#pragma unroll
      for (int dt = 0; dt < 4; ++dt) {
        const __bf16* vr = &Vt[(dt * 16 + l16) * 72];
        o_acc[dt] = MFMA16(lds8(vr + quad * 8), pf0, o_acc[dt]);
        o_acc[dt] = MFMA16(lds8(vr + 32 + quad * 8), pf1, o_acc[dt]);
      }
    }

    // o_acc[dt][r] = O[q=qrow][d=dt*16+quad*4+r]
    const float inv = 1.f / l_s;
#pragma unroll
    for (int dt = 0; dt < 4; ++dt) {
      bf16x4 ov;
#pragma unroll
      for (int r = 0; r < 4; ++r) ov[r] = (__bf16)(o_acc[dt][r] * inv);
      *reinterpret_cast<bf16x4*>(&Oh[(size_t)qrow * Dd + dt * 16 + quad * 4]) = ov;
    }
  }
}

// ---------------------------------------------------------------------------
// Proj GEMM (m97 structure): y(f32)[4096,1024] = O([B,H,T,D]) @ WT[1024,1024]^T + b
// ---------------------------------------------------------------------------
__global__ __launch_bounds__(256) void proj_gemm(
    const __hip_bfloat16* __restrict__ O, const __hip_bfloat16* __restrict__ WT,
    const float* __restrict__ bias, float* __restrict__ out) {
  __shared__ __hip_bfloat16 As[128 * 32];
  __shared__ __hip_bfloat16 Bs[128 * 32];
  const int tid = threadIdx.x;
  const int wave = tid >> 6, lane = tid & 63;
  const int l16 = lane & 15, quad = lane >> 4;
  const int m0 = blockIdx.y * 128, n0 = blockIdx.x * 128;
  const int wm = (wave >> 1) * 64, wn = (wave & 1) * 64;

  const int srow = wave * 32 + (lane >> 2);
  const int kseg = (lane & 3) * 8;

  f32x4 acc[4][4] = {};

  for (int k0 = 0; k0 < Cc; k0 += 32) {
    const int k = k0 + kseg;  // channel = h*64+d; 8-seg never crosses a head
    const int h = k >> 6, d = k & 63;
    __syncthreads();
#pragma unroll
    for (int j = 0; j < 2; ++j) {
      const int m = m0 + srow + j * 16;
      const int b = m >> 11, t = m & 2047;
      load_lds16(O + ((size_t)(b * Hh + h) * Tt + t) * Dd + d,
                 As + (wave * 32 + j * 16) * 32);
      load_lds16(WT + (size_t)(n0 + srow + j * 16) * Cc + k0 + kseg,
                 Bs + (wave * 32 + j * 16) * 32);
    }
    __syncthreads();

    bf16x8 af[4], bfr[4];
#pragma unroll
    for (int i = 0; i < 4; ++i) {
      af[i] = ldg8(As + (wm + i * 16 + l16) * 32 + quad * 8);
      bfr[i] = ldg8(Bs + (wn + i * 16 + l16) * 32 + quad * 8);
    }
#pragma unroll
    for (int i = 0; i < 4; ++i)
#pragma unroll
      for (int jn = 0; jn < 4; ++jn)
        acc[i][jn] = MFMA16(af[i], bfr[jn], acc[i][jn]);
  }

#pragma unroll
  for (int jn = 0; jn < 4; ++jn) {
    const int n = n0 + wn + jn * 16 + l16;
    const float bv = bias[n];
#pragma unroll
    for (int i = 0; i < 4; ++i)
#pragma unroll
      for (int r = 0; r < 4; ++r) {
        const int m = m0 + wm + i * 16 + quad * 4 + r;
        out[(size_t)m * Cc + n] = acc[i][jn][r] + bv;
      }
  }
}

// ---------------------------------------------------------------------------
extern "C" void kernel_launch(void* const* d_in, const int* in_sizes, int n_in,
                              void* d_out, int out_size, void* d_ws, size_t ws_size,
                              hipStream_t stream) {
  const float* x      = (const float*)d_in[0];
  const float* W_qkv  = (const float*)d_in[1];
  const float* b_qkv  = (const float*)d_in[2];
  const float* W_proj = (const float*)d_in[3];
  const float* b_proj = (const float*)d_in[4];
  float* out = (float*)d_out;

  __hip_bfloat16* ws = (__hip_bfloat16*)d_ws;
  const size_t NBHTD = (size_t)Bb * Hh * Tt * Dd;  // 4,194,304
  __hip_bfloat16* Qw  = ws;
  __hip_bfloat16* Kw  = ws + NBHTD;
  __hip_bfloat16* VTw = ws + 2 * NBHTD;
  __hip_bfloat16* Ow  = ws + 3 * NBHTD;
  __hip_bfloat16* xb  = ws + 4 * NBHTD;                  // [4096,1024]
  __hip_bfloat16* WTqkv  = xb + NBHTD;                   // [3072,1024]
  __hip_bfloat16* WTproj = WTqkv + (size_t)3 * Cc * Cc;  // [1024,1024]

  cvt_f32_bf16<<<dim3(4096), dim3(256), 0, stream>>>(x, xb, Bb * Tt * Cc);
  transpose_cvt<<<dim3(96, 32), dim3(32, 8), 0, stream>>>(W_qkv, WTqkv, Cc, 3 * Cc);
  transpose_cvt<<<dim3(32, 32), dim3(32, 8), 0, stream>>>(W_proj, WTproj, Cc, Cc);
  qkv_gemm<<<dim3(24, 32), 256, 0, stream>>>(xb, WTqkv, b_qkv, Qw, Kw, VTw);
  attn<<<dim3(Tt / 128, Hh, Bb), 256, 0, stream>>>(Qw, Kw, VTw, Ow);
  proj_gemm<<<dim3(8, 32), 256, 0, stream>>>(Ow, WTproj, b_proj, out);
}

// Round 7
// 201.966 us; speedup vs baseline: 2.9866x; 1.0291x over previous
//
#include <hip/hip_runtime.h>
#include <hip/hip_bf16.h>

// Problem: B=2, T=2048, C=1024, H=16, D=64. Tensors stored f32; compute bf16 MFMA.
#define Bb 2
#define Tt 2048
#define Cc 1024
#define Hh 16
#define Dd 64

typedef __bf16 bf16x8 __attribute__((ext_vector_type(8)));
typedef __bf16 bf16x4 __attribute__((ext_vector_type(4)));
typedef float f32x4 __attribute__((ext_vector_type(4)));

#define MFMA16(a, b, c) __builtin_amdgcn_mfma_f32_16x16x32_bf16((a), (b), (c), 0, 0, 0)

__device__ __forceinline__ bf16x8 ldg8(const __hip_bfloat16* p) {
  return *reinterpret_cast<const bf16x8*>(p);
}
__device__ __forceinline__ bf16x8 lds8(const __bf16* p) {
  return *reinterpret_cast<const bf16x8*>(p);
}

// Async global->LDS, 16B per lane. LDS dest = wave-uniform base + lane*16.
__device__ __forceinline__ void load_lds16(const __hip_bfloat16* g, __hip_bfloat16* l) {
  __builtin_amdgcn_global_load_lds(
      (const __attribute__((address_space(1))) void*)g,
      (__attribute__((address_space(3))) void*)l, 16, 0, 0);
}

// ---------------------------------------------------------------------------
// f32 -> bf16 elementwise cast
// ---------------------------------------------------------------------------
__global__ __launch_bounds__(256) void cvt_f32_bf16(
    const float* __restrict__ in, __hip_bfloat16* __restrict__ out, int n) {
  const int i = (blockIdx.x * 256 + threadIdx.x) * 4;
  if (i + 3 < n) {
    const float4 v = *reinterpret_cast<const float4*>(in + i);
    out[i + 0] = __float2bfloat16(v.x);
    out[i + 1] = __float2bfloat16(v.y);
    out[i + 2] = __float2bfloat16(v.z);
    out[i + 3] = __float2bfloat16(v.w);
  }
}

// ---------------------------------------------------------------------------
// Transpose+cast: in f32 [R][Cn] row-major -> out bf16 [Cn][R]
// ---------------------------------------------------------------------------
__global__ __launch_bounds__(256) void transpose_cvt(
    const float* __restrict__ in, __hip_bfloat16* __restrict__ out,
    int R, int Cn) {
  __shared__ float tile[32][33];
  const int c0 = blockIdx.x * 32, r0 = blockIdx.y * 32;
  const int tx = threadIdx.x, ty = threadIdx.y;  // block (32,8)
#pragma unroll
  for (int i = 0; i < 32; i += 8)
    tile[ty + i][tx] = in[(size_t)(r0 + ty + i) * Cn + c0 + tx];
  __syncthreads();
#pragma unroll
  for (int i = 0; i < 32; i += 8)
    out[(size_t)(c0 + ty + i) * R + r0 + tx] = __float2bfloat16(tile[tx][ty + i]);
}

// ---------------------------------------------------------------------------
// QKV GEMM (m97 structure): xb[4096,1024] @ WT[3072,1024]^T + b
// ---------------------------------------------------------------------------
__global__ __launch_bounds__(256) void qkv_gemm(
    const __hip_bfloat16* __restrict__ x, const __hip_bfloat16* __restrict__ WT,
    const float* __restrict__ bias,
    __hip_bfloat16* __restrict__ Q, __hip_bfloat16* __restrict__ Kd,
    __hip_bfloat16* __restrict__ VT) {
  __shared__ __hip_bfloat16 As[128 * 32];
  __shared__ __hip_bfloat16 Bs[128 * 32];
  const int tid = threadIdx.x;
  const int wave = tid >> 6, lane = tid & 63;
  const int l16 = lane & 15, quad = lane >> 4;
  const int m0 = blockIdx.y * 128, n0 = blockIdx.x * 128;
  const int wm = (wave >> 1) * 64, wn = (wave & 1) * 64;

  const int srow = wave * 32 + (lane >> 2);
  const int kseg = (lane & 3) * 8;

  f32x4 acc[4][4] = {};

  for (int k0 = 0; k0 < Cc; k0 += 32) {
    __syncthreads();
#pragma unroll
    for (int j = 0; j < 2; ++j) {
      load_lds16(x + (size_t)(m0 + srow + j * 16) * Cc + k0 + kseg,
                 As + (wave * 32 + j * 16) * 32);
      load_lds16(WT + (size_t)(n0 + srow + j * 16) * Cc + k0 + kseg,
                 Bs + (wave * 32 + j * 16) * 32);
    }
    __syncthreads();

    bf16x8 af[4], bfr[4];
#pragma unroll
    for (int i = 0; i < 4; ++i) {
      af[i] = ldg8(As + (wm + i * 16 + l16) * 32 + quad * 8);
      bfr[i] = ldg8(Bs + (wn + i * 16 + l16) * 32 + quad * 8);
    }
#pragma unroll
    for (int i = 0; i < 4; ++i)
#pragma unroll
      for (int jn = 0; jn < 4; ++jn)
        acc[i][jn] = MFMA16(af[i], bfr[jn], acc[i][jn]);
  }

  const int sect = n0 >> 10;  // 0=Q 1=K 2=V (uniform per block)
#pragma unroll
  for (int jn = 0; jn < 4; ++jn) {
    const int n = n0 + wn + jn * 16 + l16;
    const float bv = bias[n];
    const int ch = n & 1023;
    const int h = ch >> 6, d = ch & 63;
#pragma unroll
    for (int i = 0; i < 4; ++i) {
#pragma unroll
      for (int r = 0; r < 4; ++r) {
        const int m = m0 + wm + i * 16 + quad * 4 + r;
        const int b = m >> 11, t = m & 2047;
        const __hip_bfloat16 o = __float2bfloat16(acc[i][jn][r] + bv);
        const int bh = b * Hh + h;
        if (sect == 0)      Q[((size_t)bh * Tt + t) * Dd + d] = o;
        else if (sect == 1) Kd[((size_t)bh * Tt + t) * Dd + d] = o;
        else                VT[((size_t)bh * Dd + d) * Tt + t] = o;
      }
    }
  }
}

// ---------------------------------------------------------------------------
// Flash attention v5: merged causal pair — ONE K-loop serves both q-tiles
// {qbA=bx, qbB=31-bx}. Per staged K/V tile: far tile always updated, near
// tile only while kt0<=qbA. Uniform 33 tile-updates/block; staging, barriers
// and HBM fetch amortized 2x vs v4. Diagonal masking only on kt0==qb.
// ---------------------------------------------------------------------------
__global__ __launch_bounds__(256) void attn(
    const __hip_bfloat16* __restrict__ Q, const __hip_bfloat16* __restrict__ K,
    const __hip_bfloat16* __restrict__ VT, __hip_bfloat16* __restrict__ O) {
  const int tid = threadIdx.x;
  const int wave = tid >> 6, lane = tid & 63;
  const int l16 = lane & 15, quad = lane >> 4;
  const int bh = blockIdx.z * Hh + blockIdx.y;

  const __hip_bfloat16* Qh = Q + (size_t)bh * Tt * Dd;
  const __hip_bfloat16* Kh = K + (size_t)bh * Tt * Dd;
  const __hip_bfloat16* Vh = VT + (size_t)bh * Dd * Tt;
  __hip_bfloat16* Oh = O + (size_t)bh * Tt * Dd;

  __shared__ __align__(16) __bf16 Kt[64 * 72];
  __shared__ __align__(16) __bf16 Vt[64 * 72];
  __shared__ __align__(16) __bf16 Pt[4][16 * 72];

  const float SC = 0.18033688011112042f;  // (1/sqrt(64)) * log2(e)
  const int skey = tid >> 3, sd = (tid & 7) * 8;

  const int qbA = blockIdx.x;            // near q-tile
  const int qbB = (Tt / 64 - 1) - qbA;   // far q-tile
  const int qrowA = qbA * 64 + wave * 16 + l16;
  const int qrowB = qbB * 64 + wave * 16 + l16;

  const bf16x8 qA0 = ldg8(Qh + (size_t)qrowA * Dd + quad * 8);
  const bf16x8 qA1 = ldg8(Qh + (size_t)qrowA * Dd + 32 + quad * 8);
  const bf16x8 qB0 = ldg8(Qh + (size_t)qrowB * Dd + quad * 8);
  const bf16x8 qB1 = ldg8(Qh + (size_t)qrowB * Dd + 32 + quad * 8);

  f32x4 oA[4] = {}, oB[4] = {};
  float mA = -INFINITY, lA = 0.f, mB = -INFINITY, lB = 0.f;

  const int nkB = qbB + 1;

  // Prologue prefetch (tile 0).
  bf16x8 ka = ldg8(Kh + (size_t)skey * Dd + sd);
  bf16x8 kb = ldg8(Kh + (size_t)(32 + skey) * Dd + sd);
  bf16x8 va = ldg8(Vh + (size_t)skey * Tt + sd);
  bf16x8 vb = ldg8(Vh + (size_t)(32 + skey) * Tt + sd);

  auto process = [&](const bf16x8& q0f, const bf16x8& q1f, f32x4* oacc,
                     float& m_s, float& l_s, int qrow, int k0, bool diag) {
    // S^T tiles: D[m=key(kt*16+quad*4+r)][n=q(l16)]
    f32x4 st[4];
#pragma unroll
    for (int kt = 0; kt < 4; ++kt) {
      const __bf16* kr = &Kt[(kt * 16 + l16) * 72 + quad * 8];
      f32x4 z = {};
      z = MFMA16(lds8(kr), q0f, z);
      st[kt] = MFMA16(lds8(kr + 32), q1f, z);
    }
    float v[16];
    float mx = -INFINITY;
    if (diag) {  // wave-uniform branch: mask only on the diagonal tile
#pragma unroll
      for (int kt = 0; kt < 4; ++kt)
#pragma unroll
        for (int r = 0; r < 4; ++r) {
          const int key = k0 + kt * 16 + quad * 4 + r;
          const float val = (key <= qrow) ? st[kt][r] * SC : -INFINITY;
          v[kt * 4 + r] = val;
          mx = fmaxf(mx, val);
        }
    } else {
#pragma unroll
      for (int kt = 0; kt < 4; ++kt)
#pragma unroll
        for (int r = 0; r < 4; ++r) {
          const float val = st[kt][r] * SC;
          v[kt * 4 + r] = val;
          mx = fmaxf(mx, val);
        }
    }
    mx = fmaxf(mx, __shfl_xor(mx, 16, 64));
    mx = fmaxf(mx, __shfl_xor(mx, 32, 64));
    const float mnew = fmaxf(m_s, mx);
    const float alpha = exp2f(m_s - mnew);
    m_s = mnew;
    float rs = 0.f;
#pragma unroll
    for (int kt = 0; kt < 4; ++kt) {
      bf16x4 pk;
#pragma unroll
      for (int r = 0; r < 4; ++r) {
        const float p = exp2f(v[kt * 4 + r] - mnew);
        rs += p;
        pk[r] = (__bf16)p;
      }
      *reinterpret_cast<bf16x4*>(&Pt[wave][l16 * 72 + kt * 16 + quad * 4]) = pk;
    }
    rs += __shfl_xor(rs, 16, 64);
    rs += __shfl_xor(rs, 32, 64);
    l_s = l_s * alpha + rs;
#pragma unroll
    for (int dt = 0; dt < 4; ++dt) oacc[dt] *= alpha;
    // O^T += V^T·P^T (Pt wave-private; same-wave DS ordering is in-order)
    const bf16x8 pf0 = lds8(&Pt[wave][l16 * 72 + quad * 8]);
    const bf16x8 pf1 = lds8(&Pt[wave][l16 * 72 + 32 + quad * 8]);
#pragma unroll
    for (int dt = 0; dt < 4; ++dt) {
      const __bf16* vr = &Vt[(dt * 16 + l16) * 72];
      oacc[dt] = MFMA16(lds8(vr + quad * 8), pf0, oacc[dt]);
      oacc[dt] = MFMA16(lds8(vr + 32 + quad * 8), pf1, oacc[dt]);
    }
  };

  for (int kt0 = 0; kt0 < nkB; ++kt0) {
    const int k0 = kt0 * 64;
    __syncthreads();  // all waves done reading previous Kt/Vt
    *reinterpret_cast<bf16x8*>(&Kt[skey * 72 + sd]) = ka;
    *reinterpret_cast<bf16x8*>(&Kt[(32 + skey) * 72 + sd]) = kb;
    *reinterpret_cast<bf16x8*>(&Vt[skey * 72 + sd]) = va;
    *reinterpret_cast<bf16x8*>(&Vt[(32 + skey) * 72 + sd]) = vb;
    if (kt0 + 1 < nkB) {  // prefetch next tile; completes during compute
      const int k1 = k0 + 64;
      ka = ldg8(Kh + (size_t)(k1 + skey) * Dd + sd);
      kb = ldg8(Kh + (size_t)(k1 + 32 + skey) * Dd + sd);
      va = ldg8(Vh + (size_t)skey * Tt + k1 + sd);
      vb = ldg8(Vh + (size_t)(32 + skey) * Tt + k1 + sd);
    }
    __syncthreads();

    process(qB0, qB1, oB, mB, lB, qrowB, k0, kt0 == qbB);
    if (kt0 <= qbA) process(qA0, qA1, oA, mA, lA, qrowA, k0, kt0 == qbA);
  }

  const float invA = 1.f / lA, invB = 1.f / lB;
#pragma unroll
  for (int dt = 0; dt < 4; ++dt) {
    bf16x4 ovA, ovB;
#pragma unroll
    for (int r = 0; r < 4; ++r) {
      ovA[r] = (__bf16)(oA[dt][r] * invA);
      ovB[r] = (__bf16)(oB[dt][r] * invB);
    }
    *reinterpret_cast<bf16x4*>(&Oh[(size_t)qrowA * Dd + dt * 16 + quad * 4]) = ovA;
    *reinterpret_cast<bf16x4*>(&Oh[(size_t)qrowB * Dd + dt * 16 + quad * 4]) = ovB;
  }
}

// ---------------------------------------------------------------------------
// Proj GEMM (m97 structure): y(f32)[4096,1024] = O([B,H,T,D]) @ WT[1024,1024]^T + b
// ---------------------------------------------------------------------------
__global__ __launch_bounds__(256) void proj_gemm(
    const __hip_bfloat16* __restrict__ O, const __hip_bfloat16* __restrict__ WT,
    const float* __restrict__ bias, float* __restrict__ out) {
  __shared__ __hip_bfloat16 As[128 * 32];
  __shared__ __hip_bfloat16 Bs[128 * 32];
  const int tid = threadIdx.x;
  const int wave = tid >> 6, lane = tid & 63;
  const int l16 = lane & 15, quad = lane >> 4;
  const int m0 = blockIdx.y * 128, n0 = blockIdx.x * 128;
  const int wm = (wave >> 1) * 64, wn = (wave & 1) * 64;

  const int srow = wave * 32 + (lane >> 2);
  const int kseg = (lane & 3) * 8;

  f32x4 acc[4][4] = {};

  for (int k0 = 0; k0 < Cc; k0 += 32) {
    const int k = k0 + kseg;  // channel = h*64+d; 8-seg never crosses a head
    const int h = k >> 6, d = k & 63;
    __syncthreads();
#pragma unroll
    for (int j = 0; j < 2; ++j) {
      const int m = m0 + srow + j * 16;
      const int b = m >> 11, t = m & 2047;
      load_lds16(O + ((size_t)(b * Hh + h) * Tt + t) * Dd + d,
                 As + (wave * 32 + j * 16) * 32);
      load_lds16(WT + (size_t)(n0 + srow + j * 16) * Cc + k0 + kseg,
                 Bs + (wave * 32 + j * 16) * 32);
    }
    __syncthreads();

    bf16x8 af[4], bfr[4];
#pragma unroll
    for (int i = 0; i < 4; ++i) {
      af[i] = ldg8(As + (wm + i * 16 + l16) * 32 + quad * 8);
      bfr[i] = ldg8(Bs + (wn + i * 16 + l16) * 32 + quad * 8);
    }
#pragma unroll
    for (int i = 0; i < 4; ++i)
#pragma unroll
      for (int jn = 0; jn < 4; ++jn)
        acc[i][jn] = MFMA16(af[i], bfr[jn], acc[i][jn]);
  }

#pragma unroll
  for (int jn = 0; jn < 4; ++jn) {
    const int n = n0 + wn + jn * 16 + l16;
    const float bv = bias[n];
#pragma unroll
    for (int i = 0; i < 4; ++i)
#pragma unroll
      for (int r = 0; r < 4; ++r) {
        const int m = m0 + wm + i * 16 + quad * 4 + r;
        out[(size_t)m * Cc + n] = acc[i][jn][r] + bv;
      }
  }
}

// ---------------------------------------------------------------------------
extern "C" void kernel_launch(void* const* d_in, const int* in_sizes, int n_in,
                              void* d_out, int out_size, void* d_ws, size_t ws_size,
                              hipStream_t stream) {
  const float* x      = (const float*)d_in[0];
  const float* W_qkv  = (const float*)d_in[1];
  const float* b_qkv  = (const float*)d_in[2];
  const float* W_proj = (const float*)d_in[3];
  const float* b_proj = (const float*)d_in[4];
  float* out = (float*)d_out;

  __hip_bfloat16* ws = (__hip_bfloat16*)d_ws;
  const size_t NBHTD = (size_t)Bb * Hh * Tt * Dd;  // 4,194,304
  __hip_bfloat16* Qw  = ws;
  __hip_bfloat16* Kw  = ws + NBHTD;
  __hip_bfloat16* VTw = ws + 2 * NBHTD;
  __hip_bfloat16* Ow  = ws + 3 * NBHTD;
  __hip_bfloat16* xb  = ws + 4 * NBHTD;                  // [4096,1024]
  __hip_bfloat16* WTqkv  = xb + NBHTD;                   // [3072,1024]
  __hip_bfloat16* WTproj = WTqkv + (size_t)3 * Cc * Cc;  // [1024,1024]

  cvt_f32_bf16<<<dim3(4096), dim3(256), 0, stream>>>(x, xb, Bb * Tt * Cc);
  transpose_cvt<<<dim3(96, 32), dim3(32, 8), 0, stream>>>(W_qkv, WTqkv, Cc, 3 * Cc);
  transpose_cvt<<<dim3(32, 32), dim3(32, 8), 0, stream>>>(W_proj, WTproj, Cc, Cc);
  qkv_gemm<<<dim3(24, 32), 256, 0, stream>>>(xb, WTqkv, b_qkv, Qw, Kw, VTw);
  attn<<<dim3(Tt / 128, Hh, Bb), 256, 0, stream>>>(Qw, Kw, VTw, Ow);
  proj_gemm<<<dim3(8, 32), 256, 0, stream>>>(Ow, WTproj, b_proj, out);
}